// Round 8
// baseline (429.429 us; speedup 1.0000x reference)
//
#include <hip/hip_runtime.h>

// ---------- types ----------
typedef __attribute__((ext_vector_type(8))) short bf16x8;
typedef __attribute__((ext_vector_type(4))) float f32x4;

#define T_SEQ   2048
#define DIM     3072
#define NQH     32
#define NKVH    8
#define HD      128
#define QDIM    4096
#define KVDIM   1024
#define QKVDIM  6144

#define AS1 __attribute__((address_space(1)))
#define AS3 __attribute__((address_space(3)))

static __device__ __forceinline__ unsigned short f2bf(float f) {
  unsigned u = __float_as_uint(f);
  u += 0x7FFFu + ((u >> 16) & 1u);          // RNE
  return (unsigned short)(u >> 16);
}
static __device__ __forceinline__ float bf2f(unsigned short h) {
  return __uint_as_float(((unsigned)h) << 16);
}
// packed f32x2 -> bf16x2 (RNE), 1 instruction
static __device__ __forceinline__ unsigned pkbf(float lo, float hi) {
  unsigned r;
  asm("v_cvt_pk_bf16_f32 %0, %1, %2" : "=v"(r) : "v"(lo), "v"(hi));
  return r;
}

// async global->LDS, 16B per lane; LDS dest must be linear in lane order (rule 21)
static __device__ __forceinline__ void gload_lds16(const unsigned short* g, unsigned short* l) {
  __builtin_amdgcn_global_load_lds((AS1 void*)(g), (AS3 void*)(l), 16, 0, 0);
}

// ---------- fp32 -> bf16 convert (vectorized) ----------
__global__ void cvt_f32_bf16(const float* __restrict__ src, unsigned short* __restrict__ dst, int n4) {
  int i = blockIdx.x * blockDim.x + threadIdx.x;
  if (i >= n4) return;
  float4 v = reinterpret_cast<const float4*>(src)[i];
  ushort4 o;
  o.x = f2bf(v.x); o.y = f2bf(v.y); o.z = f2bf(v.z); o.w = f2bf(v.w);
  reinterpret_cast<ushort4*>(dst)[i] = o;
}

// ---------- GEMM: C[M,N] = A[M,K] * B[N,K]^T, bf16 in, f32 or bf16 out ----------
// 256x256 tile, 512 threads = 8 waves (2M x 4N, 128x64 per wave), BK=32.
// Deep pipeline (T3+T4): 4-deep LDS ring staged by global_load_lds (linear,
// no swizzle needed: 64B rows spread a column-slice b128 read uniformly over
// all banks), prefetch 3 K-tiles ahead, counted s_waitcnt vmcnt(8/4/0) with
// RAW s_barrier (loads stay in flight across barriers), 2 x 16-MFMA phases
// with lgkmcnt(0)+sched_barrier (rule 18) and setprio around MFMA (T5).
// Chunk ci (8 shorts = 16B): LDS offset ci*8 shorts — linear in lane order.
template<int OUTBF>
__global__ __launch_bounds__(512, 2) void gemm256(
    const unsigned short* __restrict__ A, const unsigned short* __restrict__ B,
    float* __restrict__ Cf, unsigned short* __restrict__ Cb,
    int M, int N, int K) {
  __shared__ unsigned short ldsA[4][256 * 32];
  __shared__ unsigned short ldsB[4][256 * 32];
  const int nbx = N >> 8;
  const int q8 = gridDim.x >> 3;            // grid % 8 == 0 guaranteed by launch
  int bid = blockIdx.x;
  bid = (bid & 7) * q8 + (bid >> 3);        // XCD-contiguous (one M-panel per XCD)
  const int bx = bid % nbx, by = bid / nbx;
  const int tid = threadIdx.x;
  const int ln = tid & 63;
  const int wave = tid >> 6;
  const int lr = ln & 15, lg = ln >> 4;
  const int wr = wave >> 2, wc = wave & 3;  // 2M x 4N wave grid
  const int rowA0 = by << 8, rowB0 = bx << 8;

  // per-thread staging chunk roles: chunk ci in [0,1024): r = ci>>2, cp = ci&3
  const int ci0 = tid, ci1 = tid + 512;
  const int r0 = ci0 >> 2, cp0 = ci0 & 3;
  const int r1 = ci1 >> 2, cp1 = ci1 & 3;

  f32x4 acc[8][4] = {};

  const int ktn = K >> 5;

  // issue one K-tile's staging: 4 global_load_lds per thread (A x2, B x2)
  auto STAGE = [&](int kt, int bufi) {
    const unsigned short* Ak = A + (size_t)kt * 32;
    const unsigned short* Bk = B + (size_t)kt * 32;
    gload_lds16(Ak + (size_t)(rowA0 + r0) * K + cp0 * 8, &ldsA[bufi][ci0 * 8]);
    gload_lds16(Ak + (size_t)(rowA0 + r1) * K + cp1 * 8, &ldsA[bufi][ci1 * 8]);
    gload_lds16(Bk + (size_t)(rowB0 + r0) * K + cp0 * 8, &ldsB[bufi][ci0 * 8]);
    gload_lds16(Bk + (size_t)(rowB0 + r1) * K + cp1 * 8, &ldsB[bufi][ci1 * 8]);
  };

  // prologue: prefetch tiles 0,1,2 (12 loads); wait tile 0 (8 left in flight)
  STAGE(0, 0); STAGE(1, 1); STAGE(2, 2);
  asm volatile("s_waitcnt vmcnt(8)" ::: "memory");
  __builtin_amdgcn_s_barrier();

  for (int t = 0; t < ktn; t++) {
    const int c = t & 3;
    if (t + 3 < ktn) STAGE(t + 3, (t + 3) & 3);   // ring slot read in iter t-1

    // ---- phase 0: B frags + A frags (M 0..3), 16 MFMA ----
    bf16x8 bf_[4], af_[4];
#pragma unroll
    for (int ni = 0; ni < 4; ni++)
      bf_[ni] = *reinterpret_cast<const bf16x8*>(&ldsB[c][(wc * 64 + ni * 16 + lr) * 32 + lg * 8]);
#pragma unroll
    for (int mi = 0; mi < 4; mi++)
      af_[mi] = *reinterpret_cast<const bf16x8*>(&ldsA[c][(wr * 128 + mi * 16 + lr) * 32 + lg * 8]);
    asm volatile("s_waitcnt lgkmcnt(0)" ::: "memory");
    __builtin_amdgcn_sched_barrier(0);
    __builtin_amdgcn_s_setprio(1);
#pragma unroll
    for (int mi = 0; mi < 4; mi++)
#pragma unroll
      for (int ni = 0; ni < 4; ni++)
        acc[mi][ni] = __builtin_amdgcn_mfma_f32_16x16x32_bf16(af_[mi], bf_[ni], acc[mi][ni], 0, 0, 0);
    __builtin_amdgcn_s_setprio(0);

    // ---- phase 1: A frags (M 4..7), 16 MFMA ----
    bf16x8 ag_[4];
#pragma unroll
    for (int mi = 0; mi < 4; mi++)
      ag_[mi] = *reinterpret_cast<const bf16x8*>(&ldsA[c][(wr * 128 + (mi + 4) * 16 + lr) * 32 + lg * 8]);
    asm volatile("s_waitcnt lgkmcnt(0)" ::: "memory");
    __builtin_amdgcn_sched_barrier(0);
    __builtin_amdgcn_s_setprio(1);
#pragma unroll
    for (int mi = 0; mi < 4; mi++)
#pragma unroll
      for (int ni = 0; ni < 4; ni++)
        acc[mi + 4][ni] = __builtin_amdgcn_mfma_f32_16x16x32_bf16(ag_[mi], bf_[ni], acc[mi + 4][ni], 0, 0, 0);
    __builtin_amdgcn_s_setprio(0);

    // ---- counted wait: ensure tile t+1 landed; keep later tiles in flight ----
    if (t < ktn - 3)       { asm volatile("s_waitcnt vmcnt(8)" ::: "memory"); }
    else if (t == ktn - 3) { asm volatile("s_waitcnt vmcnt(4)" ::: "memory"); }
    else if (t == ktn - 2) { asm volatile("s_waitcnt vmcnt(0)" ::: "memory"); }
    if (t < ktn - 1) __builtin_amdgcn_s_barrier();
  }

  // ---- epilogue: C write ----
#pragma unroll
  for (int mi = 0; mi < 8; mi++)
#pragma unroll
    for (int ni = 0; ni < 4; ni++)
#pragma unroll
      for (int j = 0; j < 4; j++) {
        int r = rowA0 + wr * 128 + mi * 16 + lg * 4 + j;   // C/D: row=(l>>4)*4+j, col=l&15
        int cc = rowB0 + wc * 64 + ni * 16 + lr;
        if (OUTBF) Cb[(size_t)r * N + cc] = f2bf(acc[mi][ni][j]);
        else       Cf[(size_t)r * N + cc] = acc[mi][ni][j];
      }
}

// ---------- RoPE + repack: qkv bf16 [T,6144] -> q [T,4096], k [T,1024] ----------
__global__ void rope_repack(const unsigned short* __restrict__ qkv,
                            const float* __restrict__ fc, const float* __restrict__ fs,
                            unsigned short* __restrict__ qo, unsigned short* __restrict__ ko) {
  int idx = blockIdx.x * blockDim.x + threadIdx.x;   // T * 40 * 64
  int d = idx & 63;
  int hh = (idx >> 6) % 40;                          // 0..31 q heads, 32..39 k heads
  int t = idx / 2560;
  const unsigned short* src = qkv + (size_t)t * QKVDIM + hh * 128;
  float x0 = bf2f(src[d]);
  float x1 = bf2f(src[d + 64]);
  float c = fc[t * 64 + d], s = fs[t * 64 + d];
  float o0 = x0 * c - x1 * s;
  float o1 = x1 * c + x0 * s;
  if (hh < 32) {
    unsigned short* dst = qo + (size_t)t * QDIM + hh * 128;
    dst[d] = f2bf(o0); dst[d + 64] = f2bf(o1);
  } else {
    unsigned short* dst = ko + (size_t)t * KVDIM + (hh - 32) * 128;
    dst[d] = f2bf(o0); dst[d + 64] = f2bf(o1);
  }
}

// ---------- V transpose: qkv[:,5120+c] -> vt[c][t]  (c = kh*128+d) ----------
__global__ void vtrans(const unsigned short* __restrict__ qkv, unsigned short* __restrict__ vt) {
  __shared__ unsigned short tile[64][68];
  int tb = blockIdx.x * 64, cb = blockIdx.y * 64;
  int tid = threadIdx.x;
#pragma unroll
  for (int i = 0; i < 16; i++) {
    int e = i * 256 + tid;
    int tl = e >> 6, cl = e & 63;
    tile[tl][cl] = qkv[(size_t)(tb + tl) * QKVDIM + 5120 + cb + cl];
  }
  __syncthreads();
#pragma unroll
  for (int i = 0; i < 16; i++) {
    int e = i * 256 + tid;
    int cl = e >> 6, tl = e & 63;
    vt[(size_t)(cb + cl) * T_SEQ + tb + tl] = tile[tl][cl];
  }
}

// ---------- causal GQA flash attention ----------
// 512 uniform-work blocks: each processes q-tiles (pr, 31-pr) of one head in a
// SINGLE shared s-loop (K/V staged once; heavy tile always computes, light tile
// only while in range) -> per-block work constant, no CU drain. kv-head = bid&7
// pins K/V to one XCD's L2. Swapped QK^T keeps softmax lane-local; P packed with
// v_cvt_pk_bf16_f32 (T12); defer-rescale (T13); dbuf LDS, 1 barrier/tile.
__global__ __launch_bounds__(256) void attn_fwd(
    const unsigned short* __restrict__ q, const unsigned short* __restrict__ k,
    const unsigned short* __restrict__ vt, unsigned short* __restrict__ y) {
  __shared__ unsigned short k_lds[2][32 * 128];    // [s][chunk p*8], p = (d/8) ^ (s&7)
  __shared__ unsigned short v_lds[2][128 * 32];    // [d][chunk p*8], p = (s/8) ^ ((d/2)&3)
  __shared__ unsigned short p_lds[4][16 * 40];     // per-wave P, padded stride 40
  __shared__ float a_lds[4][16];
  const int tid = threadIdx.x;
  const int ln = tid & 63;
  const int wave = tid >> 6;
  const int lr = ln & 15, lg = ln >> 4;

  // bid -> (kv-head = XCD, q-head, q-tile pair)
  const int kh = blockIdx.x & 7;
  const int i = blockIdx.x >> 3;                   // 0..63
  const int qh = i & 3;
  const int pr = i >> 2;                           // 0..15
  const int qta = pr, qtb = 31 - pr;               // light + heavy tile, work ~ const
  const int h = kh * 4 + qh;

  const int qra0 = qta * 64 + wave * 16, qrowa = qra0 + lr;
  const int qrb0 = qtb * 64 + wave * 16, qrowb = qrb0 + lr;
  const float SL2E = 0.08838834764831845f * 1.44269504088896f;  // scale * log2(e)
  const float NEGINF = -__builtin_inff();

  bf16x8 qfa[4], qfb[4];
  {
    const unsigned short* qba = q + (size_t)qrowa * QDIM + h * HD + lg * 8;
    const unsigned short* qbb = q + (size_t)qrowb * QDIM + h * HD + lg * 8;
#pragma unroll
    for (int dc = 0; dc < 4; dc++) {
      qfa[dc] = *reinterpret_cast<const bf16x8*>(qba + dc * 32);
      qfb[dc] = *reinterpret_cast<const bf16x8*>(qbb + dc * 32);
    }
  }

  f32x4 acca[8] = {}, accb[8] = {};
  float ma = NEGINF, la = 0.f, mb = NEGINF, lb = 0.f;

  // staging lane roles (constant per thread)
  const int krow0 = tid >> 4,  kcol0 = tid & 15;   // K chunks 0..255
  const int krow1 = 16 + krow0;                    // K chunks 256..511
  const int vrow0 = tid >> 2,  vcol0 = tid & 3;    // V chunks 0..255
  const int vrow1 = 64 + vrow0;                    // V chunks 256..511

  // one s-tile of online-softmax attention for one q-tile's 16 rows
  auto tile_compute = [&](int sb, int cur, const bf16x8 (&qf)[4], f32x4 (&acc)[8],
                          float& m, float& lsum, int qr0, int qrow) {
    // QK^T swapped: A = K rows (s), B = Q (col=q)
    f32x4 s0t = {0.f, 0.f, 0.f, 0.f}, s1t = {0.f, 0.f, 0.f, 0.f};
    __builtin_amdgcn_s_setprio(1);
#pragma unroll
    for (int dc = 0; dc < 4; dc++) {
      int c = lg + dc * 4;
      int p = c ^ (lr & 7);                        // (lr+16)&7 == lr&7
      bf16x8 a0 = *reinterpret_cast<const bf16x8*>(&k_lds[cur][lr * 128 + p * 8]);
      bf16x8 a1 = *reinterpret_cast<const bf16x8*>(&k_lds[cur][(lr + 16) * 128 + p * 8]);
      s0t = __builtin_amdgcn_mfma_f32_16x16x32_bf16(a0, qf[dc], s0t, 0, 0, 0);
      s1t = __builtin_amdgcn_mfma_f32_16x16x32_bf16(a1, qf[dc], s1t, 0, 0, 0);
    }
    __builtin_amdgcn_s_setprio(0);

    // causal mask (unscaled domain)
    float vv[8];
    if (sb + 31 <= qr0) {
#pragma unroll
      for (int jj = 0; jj < 4; jj++) { vv[jj] = s0t[jj]; vv[jj + 4] = s1t[jj]; }
    } else {
      const int base0 = sb + lg * 4;
#pragma unroll
      for (int jj = 0; jj < 4; jj++) {
        vv[jj]     = (base0 + jj      <= qrow) ? s0t[jj] : NEGINF;
        vv[jj + 4] = (base0 + jj + 16 <= qrow) ? s1t[jj] : NEGINF;
      }
    }

    // row max: 7 in-reg + 2 cross-lane
    float mx = fmaxf(fmaxf(fmaxf(vv[0], vv[1]), fmaxf(vv[2], vv[3])),
                     fmaxf(fmaxf(vv[4], vv[5]), fmaxf(vv[6], vv[7])));
    mx = fmaxf(mx, __shfl_xor(mx, 16));
    mx = fmaxf(mx, __shfl_xor(mx, 32));

    // defer-rescale (T13)
    const bool doresc = __any(mx > m + 60.0f);     // 60*scale*log2e ~ 7.7 bits headroom
    const float mn = doresc ? fmaxf(m, mx) : m;

    float p[8], ps = 0.f;
#pragma unroll
    for (int ii = 0; ii < 8; ii++) { p[ii] = exp2f((vv[ii] - mn) * SL2E); ps += p[ii]; }
    ps += __shfl_xor(ps, 16);
    ps += __shfl_xor(ps, 32);

    // stash P as bf16 A-fragments (packed converts)
    uint2 w0, w1;
    w0.x = pkbf(p[0], p[1]); w0.y = pkbf(p[2], p[3]);
    w1.x = pkbf(p[4], p[5]); w1.y = pkbf(p[6], p[7]);
    *reinterpret_cast<uint2*>(&p_lds[wave][lr * 40 + lg * 4])      = w0;
    *reinterpret_cast<uint2*>(&p_lds[wave][lr * 40 + 16 + lg * 4]) = w1;

    if (doresc) {
      const float alpha = exp2f((m - mn) * SL2E);
      lsum = lsum * alpha + ps;
      m = mn;
      a_lds[wave][lr] = alpha;
      asm volatile("s_waitcnt lgkmcnt(0)" ::: "memory");
      float4 a4 = *reinterpret_cast<const float4*>(&a_lds[wave][lg * 4]);
#pragma unroll
      for (int dc2 = 0; dc2 < 8; dc2++) {
        acc[dc2][0] *= a4.x; acc[dc2][1] *= a4.y;
        acc[dc2][2] *= a4.z; acc[dc2][3] *= a4.w;
      }
    } else {
      lsum += ps;
      asm volatile("s_waitcnt lgkmcnt(0)" ::: "memory");
    }

    bf16x8 pa = *reinterpret_cast<const bf16x8*>(&p_lds[wave][lr * 40 + lg * 8]);
    __builtin_amdgcn_s_setprio(1);
#pragma unroll
    for (int dc2 = 0; dc2 < 8; dc2++) {
      int d = dc2 * 16 + lr;
      int p2 = lg ^ ((d >> 1) & 3);
      bf16x8 bv = *reinterpret_cast<const bf16x8*>(&v_lds[cur][d * 32 + p2 * 8]);
      acc[dc2] = __builtin_amdgcn_mfma_f32_16x16x32_bf16(pa, bv, acc[dc2], 0, 0, 0);
    }
    __builtin_amdgcn_s_setprio(0);
  };

  const int ntiles = (qtb * 64 + 95) >> 5;         // heavy tile's range covers light's

  // ---- prologue: stage tile 0 ----
  {
    bf16x8 kr0 = *reinterpret_cast<const bf16x8*>(k + (size_t)krow0 * KVDIM + kh * HD + kcol0 * 8);
    bf16x8 kr1 = *reinterpret_cast<const bf16x8*>(k + (size_t)krow1 * KVDIM + kh * HD + kcol0 * 8);
    bf16x8 vr0 = *reinterpret_cast<const bf16x8*>(vt + (size_t)(kh * HD + vrow0) * T_SEQ + vcol0 * 8);
    bf16x8 vr1 = *reinterpret_cast<const bf16x8*>(vt + (size_t)(kh * HD + vrow1) * T_SEQ + vcol0 * 8);
    *reinterpret_cast<bf16x8*>(&k_lds[0][krow0 * 128 + (kcol0 ^ (krow0 & 7)) * 8]) = kr0;
    *reinterpret_cast<bf16x8*>(&k_lds[0][krow1 * 128 + (kcol0 ^ (krow1 & 7)) * 8]) = kr1;
    *reinterpret_cast<bf16x8*>(&v_lds[0][vrow0 * 32 + (vcol0 ^ ((vrow0 >> 1) & 3)) * 8]) = vr0;
    *reinterpret_cast<bf16x8*>(&v_lds[0][vrow1 * 32 + (vcol0 ^ ((vrow1 >> 1) & 3)) * 8]) = vr1;
  }
  __syncthreads();

  for (int st = 0; st < ntiles; st++) {
    const int sb = st * 32;
    const int cur = st & 1;
    const bool more = (st + 1 < ntiles);

    // issue next tile's global loads (latency hides under compute)
    bf16x8 kr0, kr1, vr0, vr1;
    if (more) {
      const int sb1 = sb + 32;
      kr0 = *reinterpret_cast<const bf16x8*>(k + (size_t)(sb1 + krow0) * KVDIM + kh * HD + kcol0 * 8);
      kr1 = *reinterpret_cast<const bf16x8*>(k + (size_t)(sb1 + krow1) * KVDIM + kh * HD + kcol0 * 8);
      vr0 = *reinterpret_cast<const bf16x8*>(vt + (size_t)(kh * HD + vrow0) * T_SEQ + sb1 + vcol0 * 8);
      vr1 = *reinterpret_cast<const bf16x8*>(vt + (size_t)(kh * HD + vrow1) * T_SEQ + sb1 + vcol0 * 8);
    }

    if (sb <= qrb0 + 15) tile_compute(sb, cur, qfb, accb, mb, lb, qrb0, qrowb);
    if (sb <= qra0 + 15) tile_compute(sb, cur, qfa, acca, ma, la, qra0, qrowa);

    // write next tile into alternate buffer, single barrier
    if (more) {
      const int nxt = cur ^ 1;
      *reinterpret_cast<bf16x8*>(&k_lds[nxt][krow0 * 128 + (kcol0 ^ (krow0 & 7)) * 8]) = kr0;
      *reinterpret_cast<bf16x8*>(&k_lds[nxt][krow1 * 128 + (kcol0 ^ (krow1 & 7)) * 8]) = kr1;
      *reinterpret_cast<bf16x8*>(&v_lds[nxt][vrow0 * 32 + (vcol0 ^ ((vrow0 >> 1) & 3)) * 8]) = vr0;
      *reinterpret_cast<bf16x8*>(&v_lds[nxt][vrow1 * 32 + (vcol0 ^ ((vrow1 >> 1) & 3)) * 8]) = vr1;
      __syncthreads();
    }
  }

  // ---- epilogue: normalize + store both q-tiles ----
  a_lds[wave][lr] = 1.0f / lb;
  asm volatile("s_waitcnt lgkmcnt(0)" ::: "memory");
  float4 l4 = *reinterpret_cast<const float4*>(&a_lds[wave][lg * 4]);
  {
    float li[4] = {l4.x, l4.y, l4.z, l4.w};
#pragma unroll
    for (int jj = 0; jj < 4; jj++) {
      int r = qrb0 + lg * 4 + jj;
#pragma unroll
      for (int dc2 = 0; dc2 < 8; dc2++)
        y[(size_t)r * QDIM + h * HD + dc2 * 16 + lr] = f2bf(accb[dc2][jj] * li[jj]);
    }
  }
  a_lds[wave][lr] = 1.0f / la;
  asm volatile("s_waitcnt lgkmcnt(0)" ::: "memory");
  l4 = *reinterpret_cast<const float4*>(&a_lds[wave][lg * 4]);
  {
    float li[4] = {l4.x, l4.y, l4.z, l4.w};
#pragma unroll
    for (int jj = 0; jj < 4; jj++) {
      int r = qra0 + lg * 4 + jj;
#pragma unroll
      for (int dc2 = 0; dc2 < 8; dc2++)
        y[(size_t)r * QDIM + h * HD + dc2 * 16 + lr] = f2bf(acca[dc2][jj] * li[jj]);
    }
  }
}

// ---------- launch ----------
extern "C" void kernel_launch(void* const* d_in, const int* in_sizes, int n_in,
                              void* d_out, int out_size, void* d_ws, size_t ws_size,
                              hipStream_t stream) {
  (void)in_sizes; (void)n_in; (void)out_size; (void)ws_size;
  const float* x    = (const float*)d_in[0];
  const float* fcos = (const float*)d_in[1];
  const float* fsin = (const float*)d_in[2];
  const float* wq   = (const float*)d_in[4];
  const float* wk   = (const float*)d_in[5];
  const float* wv   = (const float*)d_in[6];
  const float* wo   = (const float*)d_in[7];
  float* out = (float*)d_out;
  char* ws = (char*)d_ws;

  // workspace layout (phase-reuse; peak 75.5 MB)
  unsigned short* x_bf    = (unsigned short*)(ws);                    // 12.6 MB [phase 1]
  unsigned short* wqkv_bf = (unsigned short*)(ws + 12582912);         // 37.7 MB [phase 1]
  unsigned short* qkv_bf  = (unsigned short*)(ws + 50331648);         // 25.2 MB [phase 1-2]
  unsigned short* q_bf    = (unsigned short*)(ws);                    // 16.8 MB [phase 2+]
  unsigned short* k_bf    = (unsigned short*)(ws + 16777216);         //  4.2 MB
  unsigned short* vt_bf   = (unsigned short*)(ws + 20971520);         //  4.2 MB
  unsigned short* y_bf    = (unsigned short*)(ws + 25165824);         // 16.8 MB
  unsigned short* wo_bf   = (unsigned short*)(ws + 50331648);         // 25.2 MB [phase 4]

  // phase 1: convert inputs, fused QKV GEMM
  cvt_f32_bf16<<<6144,  256, 0, stream>>>(x,  x_bf,               2048 * 3072 / 4);
  cvt_f32_bf16<<<12288, 256, 0, stream>>>(wq, wqkv_bf,            4096 * 3072 / 4);
  cvt_f32_bf16<<<3072,  256, 0, stream>>>(wk, wqkv_bf + 4096*3072, 1024 * 3072 / 4);
  cvt_f32_bf16<<<3072,  256, 0, stream>>>(wv, wqkv_bf + 5120*3072, 1024 * 3072 / 4);
  gemm256<1><<<192, 512, 0, stream>>>(x_bf, wqkv_bf, nullptr, qkv_bf, 2048, 6144, 3072);

  // phase 2: RoPE + repack, V transpose
  rope_repack<<<20480, 256, 0, stream>>>(qkv_bf, fcos, fsin, q_bf, k_bf);
  vtrans<<<dim3(32, 16), 256, 0, stream>>>(qkv_bf, vt_bf);

  // phase 3/4: wo convert (reuses qkv region), attention, output GEMM
  cvt_f32_bf16<<<12288, 256, 0, stream>>>(wo, wo_bf, 3072 * 4096 / 4);
  attn_fwd<<<512, 256, 0, stream>>>(q_bf, k_bf, vt_bf, y_bf);
  gemm256<0><<<96, 512, 0, stream>>>(y_bf, wo_bf, out, nullptr, 2048, 3072, 4096);
}

// Round 9
// 319.780 us; speedup vs baseline: 1.3429x; 1.3429x over previous
//
#include <hip/hip_runtime.h>

// ---------- types ----------
typedef __attribute__((ext_vector_type(8))) short bf16x8;
typedef __attribute__((ext_vector_type(4))) float f32x4;

#define T_SEQ   2048
#define DIM     3072
#define NQH     32
#define NKVH    8
#define HD      128
#define QDIM    4096
#define KVDIM   1024
#define QKVDIM  6144

#define AS1 __attribute__((address_space(1)))
#define AS3 __attribute__((address_space(3)))

static __device__ __forceinline__ unsigned short f2bf(float f) {
  unsigned u = __float_as_uint(f);
  u += 0x7FFFu + ((u >> 16) & 1u);          // RNE
  return (unsigned short)(u >> 16);
}
static __device__ __forceinline__ float bf2f(unsigned short h) {
  return __uint_as_float(((unsigned)h) << 16);
}
// packed f32x2 -> bf16x2 (RNE), 1 instruction
static __device__ __forceinline__ unsigned pkbf(float lo, float hi) {
  unsigned r;
  asm("v_cvt_pk_bf16_f32 %0, %1, %2" : "=v"(r) : "v"(lo), "v"(hi));
  return r;
}

// async global->LDS, 16B per lane; LDS dest must be linear in lane order (rule 21)
static __device__ __forceinline__ void gload_lds16(const unsigned short* g, unsigned short* l) {
  __builtin_amdgcn_global_load_lds((AS1 void*)(g), (AS3 void*)(l), 16, 0, 0);
}

// ---------- fused fp32 -> bf16 convert: x, wq, wk, wv, wo in ONE launch ----------
// grid-stride over 9,437,184 float4s; segment select by index (wave-uniform
// except at 4 boundaries). Saves 4 launch ramps vs separate kernels.
__global__ void cvt_all(const float* __restrict__ x,  const float* __restrict__ wq,
                        const float* __restrict__ wk, const float* __restrict__ wv,
                        const float* __restrict__ wo,
                        unsigned short* __restrict__ xb,
                        unsigned short* __restrict__ wqkvb,
                        unsigned short* __restrict__ wob) {
  const int N0 = 1572864;                    // x:  2048*3072/4
  const int E1 = N0 + 3145728;               // wq: 4096*3072/4
  const int E2 = E1 + 786432;                // wk: 1024*3072/4
  const int E3 = E2 + 786432;                // wv
  const int E4 = E3 + 3145728;               // wo: 3072*4096/4
  const int stride = gridDim.x * blockDim.x;
  for (int i = blockIdx.x * blockDim.x + threadIdx.x; i < E4; i += stride) {
    const float* s; unsigned short* d; int off;
    if (i < N0)      { s = x;  d = xb;               off = i; }
    else if (i < E1) { s = wq; d = wqkvb;            off = i - N0; }
    else if (i < E2) { s = wk; d = wqkvb + 12582912; off = i - E1; }
    else if (i < E3) { s = wv; d = wqkvb + 15728640; off = i - E2; }
    else             { s = wo; d = wob;              off = i - E3; }
    float4 v = reinterpret_cast<const float4*>(s)[off];
    ushort4 o;
    o.x = f2bf(v.x); o.y = f2bf(v.y); o.z = f2bf(v.z); o.w = f2bf(v.w);
    reinterpret_cast<ushort4*>(d + (size_t)off * 4)[0] = o;
  }
}

// ---------- GEMM: C[M,N] = A[M,K] * B[N,K]^T, bf16 in, f32 or bf16 out ----------
// 128x128 tile, 4 waves (2x2 of 64x64), BK=64. m97 structure: global_load_lds
// width=16 staging, linear LDS dest + pre-swizzled global source (chunk c =
// cpos ^ (r&7)); swizzled ds_read_b128 fragment reads. Proven ~870 TF here.
template<int OUTBF>
__global__ __launch_bounds__(256) void gemm_bt(
    const unsigned short* __restrict__ A, const unsigned short* __restrict__ B,
    float* __restrict__ Cf, unsigned short* __restrict__ Cb,
    int M, int N, int K) {
  __shared__ unsigned short la[128 * 64];
  __shared__ unsigned short lb[128 * 64];
  const int nbx = N >> 7;
  const int q8 = gridDim.x >> 3;            // grid % 8 == 0 guaranteed by launch
  int bid = blockIdx.x;
  bid = (bid & 7) * q8 + (bid >> 3);        // XCD-contiguous swizzle (bijective)
  const int bx = bid % nbx, by = bid / nbx;
  const int tid = threadIdx.x;
  const int ln = tid & 63;
  const int wave = tid >> 6;
  const int lr = ln & 15, lg = ln >> 4;
  const int wr = wave >> 1, wc = wave & 1;
  const int rowA0 = by << 7, rowB0 = bx << 7;

  f32x4 acc[4][4] = {};

  const int ktn = K >> 6;
  for (int kt = 0; kt < ktn; kt++) {
    __syncthreads();                        // prev tile's reads done before overwrite
#pragma unroll
    for (int it = 0; it < 4; it++) {
      int ci = it * 256 + tid;              // linear LDS chunk id (r = ci>>3, pos = ci&7)
      int r = ci >> 3, cpos = ci & 7;
      int c = cpos ^ (r & 7);               // pre-swizzled source chunk
      const unsigned short* gA = A + (size_t)(rowA0 + r) * K + kt * 64 + c * 8;
      const unsigned short* gB = B + (size_t)(rowB0 + r) * K + kt * 64 + c * 8;
      gload_lds16(gA, &la[ci * 8]);
      gload_lds16(gB, &lb[ci * 8]);
    }
    __syncthreads();                        // drains vmcnt -> tiles visible
#pragma unroll
    for (int kk = 0; kk < 2; kk++) {
      bf16x8 af[4], bfr[4];
#pragma unroll
      for (int mi = 0; mi < 4; mi++) {
        int r = wr * 64 + mi * 16 + lr;
        int p = (kk * 4 + lg) ^ (r & 7);
        af[mi] = *reinterpret_cast<const bf16x8*>(&la[r * 64 + p * 8]);
      }
#pragma unroll
      for (int ni = 0; ni < 4; ni++) {
        int r = wc * 64 + ni * 16 + lr;
        int p = (kk * 4 + lg) ^ (r & 7);
        bfr[ni] = *reinterpret_cast<const bf16x8*>(&lb[r * 64 + p * 8]);
      }
#pragma unroll
      for (int mi = 0; mi < 4; mi++)
#pragma unroll
        for (int ni = 0; ni < 4; ni++)
          acc[mi][ni] = __builtin_amdgcn_mfma_f32_16x16x32_bf16(af[mi], bfr[ni], acc[mi][ni], 0, 0, 0);
    }
  }
#pragma unroll
  for (int mi = 0; mi < 4; mi++)
#pragma unroll
    for (int ni = 0; ni < 4; ni++)
#pragma unroll
      for (int j = 0; j < 4; j++) {
        int r = rowA0 + wr * 64 + mi * 16 + lg * 4 + j;   // C/D: row=(l>>4)*4+j, col=l&15
        int cc = rowB0 + wc * 64 + ni * 16 + lr;
        if (OUTBF) Cb[(size_t)r * N + cc] = f2bf(acc[mi][ni][j]);
        else       Cf[(size_t)r * N + cc] = acc[mi][ni][j];
      }
}

// ---------- RoPE + repack: qkv bf16 [T,6144] -> q [T,4096], k [T,1024] ----------
__global__ void rope_repack(const unsigned short* __restrict__ qkv,
                            const float* __restrict__ fc, const float* __restrict__ fs,
                            unsigned short* __restrict__ qo, unsigned short* __restrict__ ko) {
  int idx = blockIdx.x * blockDim.x + threadIdx.x;   // T * 40 * 64
  int d = idx & 63;
  int hh = (idx >> 6) % 40;                          // 0..31 q heads, 32..39 k heads
  int t = idx / 2560;
  const unsigned short* src = qkv + (size_t)t * QKVDIM + hh * 128;
  float x0 = bf2f(src[d]);
  float x1 = bf2f(src[d + 64]);
  float c = fc[t * 64 + d], s = fs[t * 64 + d];
  float o0 = x0 * c - x1 * s;
  float o1 = x1 * c + x0 * s;
  if (hh < 32) {
    unsigned short* dst = qo + (size_t)t * QDIM + hh * 128;
    dst[d] = f2bf(o0); dst[d + 64] = f2bf(o1);
  } else {
    unsigned short* dst = ko + (size_t)t * KVDIM + (hh - 32) * 128;
    dst[d] = f2bf(o0); dst[d + 64] = f2bf(o1);
  }
}

// ---------- V transpose: qkv[:,5120+c] -> vt[c][t]  (c = kh*128+d) ----------
__global__ void vtrans(const unsigned short* __restrict__ qkv, unsigned short* __restrict__ vt) {
  __shared__ unsigned short tile[64][68];
  int tb = blockIdx.x * 64, cb = blockIdx.y * 64;
  int tid = threadIdx.x;
#pragma unroll
  for (int i = 0; i < 16; i++) {
    int e = i * 256 + tid;
    int tl = e >> 6, cl = e & 63;
    tile[tl][cl] = qkv[(size_t)(tb + tl) * QKVDIM + 5120 + cb + cl];
  }
  __syncthreads();
#pragma unroll
  for (int i = 0; i < 16; i++) {
    int e = i * 256 + tid;
    int cl = e >> 6, tl = e & 63;
    vt[(size_t)(cb + cl) * T_SEQ + tb + tl] = tile[tl][cl];
  }
}

// ---------- causal GQA flash attention ----------
// 512 uniform-work blocks: each processes q-tiles (pr, 31-pr) of one head in a
// SINGLE shared s-loop (K/V staged once; heavy tile always computes, light tile
// only while in range) -> per-block work constant, no CU drain. kv-head = bid&7
// pins K/V to one XCD's L2. Swapped QK^T keeps softmax lane-local; P packed with
// v_cvt_pk_bf16_f32 (T12); defer-rescale (T13); dbuf LDS, 1 barrier/tile.
__global__ __launch_bounds__(256) void attn_fwd(
    const unsigned short* __restrict__ q, const unsigned short* __restrict__ k,
    const unsigned short* __restrict__ vt, unsigned short* __restrict__ y) {
  __shared__ unsigned short k_lds[2][32 * 128];    // [s][chunk p*8], p = (d/8) ^ (s&7)
  __shared__ unsigned short v_lds[2][128 * 32];    // [d][chunk p*8], p = (s/8) ^ ((d/2)&3)
  __shared__ unsigned short p_lds[4][16 * 40];     // per-wave P, padded stride 40
  __shared__ float a_lds[4][16];
  const int tid = threadIdx.x;
  const int ln = tid & 63;
  const int wave = tid >> 6;
  const int lr = ln & 15, lg = ln >> 4;

  // bid -> (kv-head = XCD, q-head, q-tile pair)
  const int kh = blockIdx.x & 7;
  const int i = blockIdx.x >> 3;                   // 0..63
  const int qh = i & 3;
  const int pr = i >> 2;                           // 0..15
  const int qta = pr, qtb = 31 - pr;               // light + heavy tile, work ~ const
  const int h = kh * 4 + qh;

  const int qra0 = qta * 64 + wave * 16, qrowa = qra0 + lr;
  const int qrb0 = qtb * 64 + wave * 16, qrowb = qrb0 + lr;
  const float SL2E = 0.08838834764831845f * 1.44269504088896f;  // scale * log2(e)
  const float NEGINF = -__builtin_inff();

  bf16x8 qfa[4], qfb[4];
  {
    const unsigned short* qba = q + (size_t)qrowa * QDIM + h * HD + lg * 8;
    const unsigned short* qbb = q + (size_t)qrowb * QDIM + h * HD + lg * 8;
#pragma unroll
    for (int dc = 0; dc < 4; dc++) {
      qfa[dc] = *reinterpret_cast<const bf16x8*>(qba + dc * 32);
      qfb[dc] = *reinterpret_cast<const bf16x8*>(qbb + dc * 32);
    }
  }

  f32x4 acca[8] = {}, accb[8] = {};
  float ma = NEGINF, la = 0.f, mb = NEGINF, lb = 0.f;

  // staging lane roles (constant per thread)
  const int krow0 = tid >> 4,  kcol0 = tid & 15;   // K chunks 0..255
  const int krow1 = 16 + krow0;                    // K chunks 256..511
  const int vrow0 = tid >> 2,  vcol0 = tid & 3;    // V chunks 0..255
  const int vrow1 = 64 + vrow0;                    // V chunks 256..511

  // one s-tile of online-softmax attention for one q-tile's 16 rows
  auto tile_compute = [&](int sb, int cur, const bf16x8 (&qf)[4], f32x4 (&acc)[8],
                          float& m, float& lsum, int qr0, int qrow) {
    // QK^T swapped: A = K rows (s), B = Q (col=q)
    f32x4 s0t = {0.f, 0.f, 0.f, 0.f}, s1t = {0.f, 0.f, 0.f, 0.f};
    __builtin_amdgcn_s_setprio(1);
#pragma unroll
    for (int dc = 0; dc < 4; dc++) {
      int c = lg + dc * 4;
      int p = c ^ (lr & 7);                        // (lr+16)&7 == lr&7
      bf16x8 a0 = *reinterpret_cast<const bf16x8*>(&k_lds[cur][lr * 128 + p * 8]);
      bf16x8 a1 = *reinterpret_cast<const bf16x8*>(&k_lds[cur][(lr + 16) * 128 + p * 8]);
      s0t = __builtin_amdgcn_mfma_f32_16x16x32_bf16(a0, qf[dc], s0t, 0, 0, 0);
      s1t = __builtin_amdgcn_mfma_f32_16x16x32_bf16(a1, qf[dc], s1t, 0, 0, 0);
    }
    __builtin_amdgcn_s_setprio(0);

    // causal mask (unscaled domain)
    float vv[8];
    if (sb + 31 <= qr0) {
#pragma unroll
      for (int jj = 0; jj < 4; jj++) { vv[jj] = s0t[jj]; vv[jj + 4] = s1t[jj]; }
    } else {
      const int base0 = sb + lg * 4;
#pragma unroll
      for (int jj = 0; jj < 4; jj++) {
        vv[jj]     = (base0 + jj      <= qrow) ? s0t[jj] : NEGINF;
        vv[jj + 4] = (base0 + jj + 16 <= qrow) ? s1t[jj] : NEGINF;
      }
    }

    // row max: 7 in-reg + 2 cross-lane
    float mx = fmaxf(fmaxf(fmaxf(vv[0], vv[1]), fmaxf(vv[2], vv[3])),
                     fmaxf(fmaxf(vv[4], vv[5]), fmaxf(vv[6], vv[7])));
    mx = fmaxf(mx, __shfl_xor(mx, 16));
    mx = fmaxf(mx, __shfl_xor(mx, 32));

    // defer-rescale (T13)
    const bool doresc = __any(mx > m + 60.0f);     // 60*scale*log2e ~ 7.7 bits headroom
    const float mn = doresc ? fmaxf(m, mx) : m;

    float p[8], ps = 0.f;
#pragma unroll
    for (int ii = 0; ii < 8; ii++) { p[ii] = exp2f((vv[ii] - mn) * SL2E); ps += p[ii]; }
    ps += __shfl_xor(ps, 16);
    ps += __shfl_xor(ps, 32);

    // stash P as bf16 A-fragments (packed converts)
    uint2 w0, w1;
    w0.x = pkbf(p[0], p[1]); w0.y = pkbf(p[2], p[3]);
    w1.x = pkbf(p[4], p[5]); w1.y = pkbf(p[6], p[7]);
    *reinterpret_cast<uint2*>(&p_lds[wave][lr * 40 + lg * 4])      = w0;
    *reinterpret_cast<uint2*>(&p_lds[wave][lr * 40 + 16 + lg * 4]) = w1;

    if (doresc) {
      const float alpha = exp2f((m - mn) * SL2E);
      lsum = lsum * alpha + ps;
      m = mn;
      a_lds[wave][lr] = alpha;
      asm volatile("s_waitcnt lgkmcnt(0)" ::: "memory");
      float4 a4 = *reinterpret_cast<const float4*>(&a_lds[wave][lg * 4]);
#pragma unroll
      for (int dc2 = 0; dc2 < 8; dc2++) {
        acc[dc2][0] *= a4.x; acc[dc2][1] *= a4.y;
        acc[dc2][2] *= a4.z; acc[dc2][3] *= a4.w;
      }
    } else {
      lsum += ps;
      asm volatile("s_waitcnt lgkmcnt(0)" ::: "memory");
    }

    bf16x8 pa = *reinterpret_cast<const bf16x8*>(&p_lds[wave][lr * 40 + lg * 8]);
    __builtin_amdgcn_s_setprio(1);
#pragma unroll
    for (int dc2 = 0; dc2 < 8; dc2++) {
      int d = dc2 * 16 + lr;
      int p2 = lg ^ ((d >> 1) & 3);
      bf16x8 bv = *reinterpret_cast<const bf16x8*>(&v_lds[cur][d * 32 + p2 * 8]);
      acc[dc2] = __builtin_amdgcn_mfma_f32_16x16x32_bf16(pa, bv, acc[dc2], 0, 0, 0);
    }
    __builtin_amdgcn_s_setprio(0);
  };

  const int ntiles = (qtb * 64 + 95) >> 5;         // heavy tile's range covers light's

  // ---- prologue: stage tile 0 ----
  {
    bf16x8 kr0 = *reinterpret_cast<const bf16x8*>(k + (size_t)krow0 * KVDIM + kh * HD + kcol0 * 8);
    bf16x8 kr1 = *reinterpret_cast<const bf16x8*>(k + (size_t)krow1 * KVDIM + kh * HD + kcol0 * 8);
    bf16x8 vr0 = *reinterpret_cast<const bf16x8*>(vt + (size_t)(kh * HD + vrow0) * T_SEQ + vcol0 * 8);
    bf16x8 vr1 = *reinterpret_cast<const bf16x8*>(vt + (size_t)(kh * HD + vrow1) * T_SEQ + vcol0 * 8);
    *reinterpret_cast<bf16x8*>(&k_lds[0][krow0 * 128 + (kcol0 ^ (krow0 & 7)) * 8]) = kr0;
    *reinterpret_cast<bf16x8*>(&k_lds[0][krow1 * 128 + (kcol0 ^ (krow1 & 7)) * 8]) = kr1;
    *reinterpret_cast<bf16x8*>(&v_lds[0][vrow0 * 32 + (vcol0 ^ ((vrow0 >> 1) & 3)) * 8]) = vr0;
    *reinterpret_cast<bf16x8*>(&v_lds[0][vrow1 * 32 + (vcol0 ^ ((vrow1 >> 1) & 3)) * 8]) = vr1;
  }
  __syncthreads();

  for (int st = 0; st < ntiles; st++) {
    const int sb = st * 32;
    const int cur = st & 1;
    const bool more = (st + 1 < ntiles);

    // issue next tile's global loads (latency hides under compute)
    bf16x8 kr0, kr1, vr0, vr1;
    if (more) {
      const int sb1 = sb + 32;
      kr0 = *reinterpret_cast<const bf16x8*>(k + (size_t)(sb1 + krow0) * KVDIM + kh * HD + kcol0 * 8);
      kr1 = *reinterpret_cast<const bf16x8*>(k + (size_t)(sb1 + krow1) * KVDIM + kh * HD + kcol0 * 8);
      vr0 = *reinterpret_cast<const bf16x8*>(vt + (size_t)(kh * HD + vrow0) * T_SEQ + sb1 + vcol0 * 8);
      vr1 = *reinterpret_cast<const bf16x8*>(vt + (size_t)(kh * HD + vrow1) * T_SEQ + sb1 + vcol0 * 8);
    }

    if (sb <= qrb0 + 15) tile_compute(sb, cur, qfb, accb, mb, lb, qrb0, qrowb);
    if (sb <= qra0 + 15) tile_compute(sb, cur, qfa, acca, ma, la, qra0, qrowa);

    // write next tile into alternate buffer, single barrier
    if (more) {
      const int nxt = cur ^ 1;
      *reinterpret_cast<bf16x8*>(&k_lds[nxt][krow0 * 128 + (kcol0 ^ (krow0 & 7)) * 8]) = kr0;
      *reinterpret_cast<bf16x8*>(&k_lds[nxt][krow1 * 128 + (kcol0 ^ (krow1 & 7)) * 8]) = kr1;
      *reinterpret_cast<bf16x8*>(&v_lds[nxt][vrow0 * 32 + (vcol0 ^ ((vrow0 >> 1) & 3)) * 8]) = vr0;
      *reinterpret_cast<bf16x8*>(&v_lds[nxt][vrow1 * 32 + (vcol0 ^ ((vrow1 >> 1) & 3)) * 8]) = vr1;
      __syncthreads();
    }
  }

  // ---- epilogue: normalize + store both q-tiles ----
  a_lds[wave][lr] = 1.0f / lb;
  asm volatile("s_waitcnt lgkmcnt(0)" ::: "memory");
  float4 l4 = *reinterpret_cast<const float4*>(&a_lds[wave][lg * 4]);
  {
    float li[4] = {l4.x, l4.y, l4.z, l4.w};
#pragma unroll
    for (int jj = 0; jj < 4; jj++) {
      int r = qrb0 + lg * 4 + jj;
#pragma unroll
      for (int dc2 = 0; dc2 < 8; dc2++)
        y[(size_t)r * QDIM + h * HD + dc2 * 16 + lr] = f2bf(accb[dc2][jj] * li[jj]);
    }
  }
  a_lds[wave][lr] = 1.0f / la;
  asm volatile("s_waitcnt lgkmcnt(0)" ::: "memory");
  l4 = *reinterpret_cast<const float4*>(&a_lds[wave][lg * 4]);
  {
    float li[4] = {l4.x, l4.y, l4.z, l4.w};
#pragma unroll
    for (int jj = 0; jj < 4; jj++) {
      int r = qra0 + lg * 4 + jj;
#pragma unroll
      for (int dc2 = 0; dc2 < 8; dc2++)
        y[(size_t)r * QDIM + h * HD + dc2 * 16 + lr] = f2bf(acca[dc2][jj] * li[jj]);
    }
  }
}

// ---------- launch ----------
extern "C" void kernel_launch(void* const* d_in, const int* in_sizes, int n_in,
                              void* d_out, int out_size, void* d_ws, size_t ws_size,
                              hipStream_t stream) {
  (void)in_sizes; (void)n_in; (void)out_size; (void)ws_size;
  const float* x    = (const float*)d_in[0];
  const float* fcos = (const float*)d_in[1];
  const float* fsin = (const float*)d_in[2];
  const float* wq   = (const float*)d_in[4];
  const float* wk   = (const float*)d_in[5];
  const float* wv   = (const float*)d_in[6];
  const float* wo   = (const float*)d_in[7];
  float* out = (float*)d_out;
  char* ws = (char*)d_ws;

  // workspace layout (phase-reuse; peak 75.5 MB)
  unsigned short* x_bf    = (unsigned short*)(ws);                    // 12.6 MB [phase 1]
  unsigned short* wqkv_bf = (unsigned short*)(ws + 12582912);         // 37.7 MB [phase 1]
  unsigned short* qkv_bf  = (unsigned short*)(ws + 50331648);         // 25.2 MB [phase 1-2]
  unsigned short* q_bf    = (unsigned short*)(ws);                    // 16.8 MB [phase 2+]
  unsigned short* k_bf    = (unsigned short*)(ws + 16777216);         //  4.2 MB
  unsigned short* vt_bf   = (unsigned short*)(ws + 20971520);         //  4.2 MB
  unsigned short* y_bf    = (unsigned short*)(ws + 25165824);         // 16.8 MB
  unsigned short* wo_bf   = (unsigned short*)(ws + 75497472);         // 25.2 MB (own region)

  // phase 1: fused converts (x + all weights, one launch), QKV GEMM
  cvt_all<<<4096, 256, 0, stream>>>(x, wq, wk, wv, wo, x_bf, wqkv_bf, wo_bf);
  gemm_bt<1><<<768, 256, 0, stream>>>(x_bf, wqkv_bf, nullptr, qkv_bf, 2048, 6144, 3072);

  // phase 2: RoPE + repack, V transpose
  rope_repack<<<20480, 256, 0, stream>>>(qkv_bf, fcos, fsin, q_bf, k_bf);
  vtrans<<<dim3(32, 16), 256, 0, stream>>>(qkv_bf, vt_bf);

  // phase 3/4: attention, output GEMM
  attn_fwd<<<512, 256, 0, stream>>>(q_bf, k_bf, vt_bf, y_bf);
  gemm_bt<0><<<384, 256, 0, stream>>>(y_bf, wo_bf, out, nullptr, 2048, 3072, 4096);
}